// Round 1
// baseline (1186.178 us; speedup 1.0000x reference)
//
#include <hip/hip_runtime.h>

// ---------------- degree / norm kernels ----------------

static __global__ void k_init_deg(float* dT, float* dE, int n) {
  int i = blockIdx.x * blockDim.x + threadIdx.x;
  if (i < n) { dT[i] = 1.0f; dE[i] = 1.0f; }  // self-loop weight 1
}

static __global__ void k_deg_accum(const int* __restrict__ col, const float* __restrict__ ew,
                                   float* __restrict__ deg, int E) {
  int e = blockIdx.x * blockDim.x + threadIdx.x;
  if (e < E) atomicAdd(&deg[col[e]], ew ? ew[e] : 1.0f);
}

static __global__ void k_to_dinv(float* dT, float* dE, int n) {
  int i = blockIdx.x * blockDim.x + threadIdx.x;
  if (i < n) {
    float a = dT[i]; dT[i] = (a > 0.f) ? rsqrtf(a) : 0.f;
    float b = dE[i]; dE[i] = (b > 0.f) ? rsqrtf(b) : 0.f;
  }
}

// ---------------- fp32 tiled GEMM: C = A(MxK) @ B(KxN) (+bias) ----------------
// K must be a multiple of 16 (512/128/64 all are).

static __global__ __launch_bounds__(256) void k_gemm(
    const float* __restrict__ A, const float* __restrict__ B,
    const float* __restrict__ bias, float* __restrict__ C,
    int M, int N, int K) {
  const int BM = 64, BN = 64, BK = 16;
  __shared__ float As[BK][BM + 1];
  __shared__ float Bs[BK][BN + 1];
  int tid = threadIdx.x;
  int tr = tid >> 4, tc = tid & 15;
  int brow = blockIdx.y * BM, bcol = blockIdx.x * BN;
  float acc[4][4] = {};
  for (int k0 = 0; k0 < K; k0 += BK) {
#pragma unroll
    for (int i = tid; i < BM * BK; i += 256) {
      int m = i >> 4, kk = i & 15;
      int gr = brow + m;
      As[kk][m] = (gr < M) ? A[(size_t)gr * K + k0 + kk] : 0.f;
    }
#pragma unroll
    for (int i = tid; i < BK * BN; i += 256) {
      int kk = i >> 6, n = i & 63;
      int gc = bcol + n;
      Bs[kk][n] = (gc < N) ? B[(size_t)(k0 + kk) * N + gc] : 0.f;
    }
    __syncthreads();
#pragma unroll
    for (int kk = 0; kk < BK; ++kk) {
      float a[4], b[4];
#pragma unroll
      for (int i = 0; i < 4; ++i) a[i] = As[kk][tr * 4 + i];
#pragma unroll
      for (int j = 0; j < 4; ++j) b[j] = Bs[kk][tc * 4 + j];
#pragma unroll
      for (int i = 0; i < 4; ++i)
#pragma unroll
        for (int j = 0; j < 4; ++j) acc[i][j] += a[i] * b[j];
    }
    __syncthreads();
  }
#pragma unroll
  for (int i = 0; i < 4; ++i) {
    int r = brow + tr * 4 + i;
    if (r >= M) continue;
#pragma unroll
    for (int j = 0; j < 4; ++j) {
      int c = bcol + tc * 4 + j;
      if (c < N) C[(size_t)r * N + c] = acc[i][j] + (bias ? bias[c] : 0.f);
    }
  }
}

// ---------------- edge scatter-aggregate: agg[col] += H[row] * dinv[row]*dinv[col]*w ----------------

template <int F>
static __global__ void k_scatter(const float* __restrict__ H, const int* __restrict__ row,
                                 const int* __restrict__ col, const float* __restrict__ ew,
                                 const float* __restrict__ dinv, float* __restrict__ agg, int E) {
  long t = (long)blockIdx.x * blockDim.x + threadIdx.x;
  int e = (int)(t / F);
  int f = (int)(t & (F - 1));
  if (e >= E) return;
  int r = row[e], c = col[e];
  float w = ew ? ew[e] : 1.0f;
  float nrm = dinv[r] * dinv[c] * w;
  atomicAdd(&agg[(size_t)c * F + f], H[(size_t)r * F + f] * nrm);
}

// out = maybe_relu(agg + Hpre * dinv^2 (self loop) + bias)
static __global__ void k_epilogue(const float* __restrict__ agg, const float* __restrict__ Hpre,
                                  const float* __restrict__ dinv, const float* __restrict__ bias,
                                  float* __restrict__ out, int n, int F, int relu) {
  int t = blockIdx.x * blockDim.x + threadIdx.x;
  if (t >= n * F) return;
  int i = t / F, f = t - i * F;
  float d = dinv[i];
  float v = agg[t] + Hpre[t] * d * d + (bias ? bias[f] : 0.f);
  if (relu) v = fmaxf(v, 0.f);
  out[t] = v;
}

// ---------------- log-softmax over 40 classes, in place ----------------

static __global__ void k_logsoftmax40(float* __restrict__ X, int n) {
  int i = blockIdx.x * blockDim.x + threadIdx.x;
  if (i >= n) return;
  float v[40];
  float m = -1e30f;
#pragma unroll
  for (int j = 0; j < 40; ++j) { v[j] = X[(size_t)i * 40 + j]; m = fmaxf(m, v[j]); }
  float s = 0.f;
#pragma unroll
  for (int j = 0; j < 40; ++j) s += expf(v[j] - m);
  float ls = logf(s) + m;
#pragma unroll
  for (int j = 0; j < 40; ++j) X[(size_t)i * 40 + j] = v[j] - ls;
}

// ---------------- link prediction: res[e] = dot64(h[dst], h[src]) ----------------

static __global__ void k_linkpred(const float* __restrict__ H2, const int* __restrict__ pos,
                                  const int* __restrict__ neg, float* __restrict__ res, int Elp) {
  int lane = threadIdx.x & 63;
  int e = blockIdx.x * (blockDim.x >> 6) + (threadIdx.x >> 6);
  if (e >= 2 * Elp) return;
  int a, b;
  if (e < Elp) { a = pos[e]; b = pos[Elp + e]; }
  else { int e2 = e - Elp; a = neg[e2]; b = neg[Elp + e2]; }
  float p = H2[(size_t)a * 64 + lane] * H2[(size_t)b * 64 + lane];
#pragma unroll
  for (int off = 32; off > 0; off >>= 1) p += __shfl_down(p, off, 64);
  if (lane == 0) res[e] = p;
}

// ---------------- launch ----------------

extern "C" void kernel_launch(void* const* d_in, const int* in_sizes, int n_in,
                              void* d_out, int out_size, void* d_ws, size_t ws_size,
                              hipStream_t stream) {
  const float* x    = (const float*)d_in[0];
  const int*   tp   = (const int*)d_in[1];   // train_pos_edge_index [2,EMP]
  const int*   ei   = (const int*)d_in[2];   // edge_index [2,EMP]
  const float* ew   = (const float*)d_in[3];
  const int*   pos  = (const int*)d_in[4];
  const int*   neg  = (const int*)d_in[5];
  const float* W1   = (const float*)d_in[6];
  const float* b1   = (const float*)d_in[7];
  const float* W2   = (const float*)d_in[8];
  const float* b2   = (const float*)d_in[9];
  const float* Wattr= (const float*)d_in[10];
  const float* battr= (const float*)d_in[11];
  const float* Watt = (const float*)d_in[12];
  const float* batt = (const float*)d_in[13];

  const int N   = in_sizes[0] / 512;  // 50000
  const int EMP = in_sizes[1] / 2;    // 800000
  const int ELP = in_sizes[4] / 2;    // 250000

  float* ws    = (float*)d_ws;
  float* dinvT = ws;
  float* dinvE = ws + N;
  float* bufA  = ws + 2 * (size_t)N;            // N*128 : h1_pre, then h2_pre
  float* bufB  = bufA + (size_t)N * 128;        // N*128 : agg1/h, then agg3
  float* bufC  = bufB + (size_t)N * 128;        // N*64  : agg2
  float* bufD  = bufC + (size_t)N * 64;         // N*64  : h2

  float* out_res  = (float*)d_out;
  float* out_attr = out_res + 2 * (size_t)ELP;
  float* out_att  = out_attr + (size_t)N * 40;

  dim3 b256(256);

  // degrees -> dinv
  k_init_deg<<<(N + 255) / 256, b256, 0, stream>>>(dinvT, dinvE, N);
  k_deg_accum<<<(EMP + 255) / 256, b256, 0, stream>>>(tp + EMP, nullptr, dinvT, EMP);
  k_deg_accum<<<(EMP + 255) / 256, b256, 0, stream>>>(ei + EMP, ew, dinvE, EMP);
  k_to_dinv<<<(N + 255) / 256, b256, 0, stream>>>(dinvT, dinvE, N);

  // conv1: h1_pre = x @ W1 ; h = relu(Agg_T(h1_pre) + b1)
  {
    dim3 grid(2, (N + 63) / 64);
    k_gemm<<<grid, b256, 0, stream>>>(x, W1, nullptr, bufA, N, 128, 512);
  }
  hipMemsetAsync(bufB, 0, (size_t)N * 128 * sizeof(float), stream);
  k_scatter<128><<<(int)(((size_t)EMP * 128 + 255) / 256), b256, 0, stream>>>(
      bufA, tp, tp + EMP, nullptr, dinvT, bufB, EMP);
  k_epilogue<<<(N * 128 + 255) / 256, b256, 0, stream>>>(bufB, bufA, dinvT, b1, bufB, N, 128, 1);

  // conv2: h2_pre = h @ W2 ; h2 = Agg_T(h2_pre) + b2
  {
    dim3 grid(1, (N + 63) / 64);
    k_gemm<<<grid, b256, 0, stream>>>(bufB, W2, nullptr, bufA, N, 64, 128);
  }
  hipMemsetAsync(bufC, 0, (size_t)N * 64 * sizeof(float), stream);
  k_scatter<64><<<(int)(((size_t)EMP * 64 + 255) / 256), b256, 0, stream>>>(
      bufA, tp, tp + EMP, nullptr, dinvT, bufC, EMP);
  k_epilogue<<<(N * 64 + 255) / 256, b256, 0, stream>>>(bufC, bufA, dinvT, b2, bufD, N, 64, 0);

  // conv3/4 share aggregation (Agg commutes with right-mult by W):
  // agg3 = Agg_E(h2) in bufB
  hipMemsetAsync(bufB, 0, (size_t)N * 64 * sizeof(float), stream);
  k_scatter<64><<<(int)(((size_t)EMP * 64 + 255) / 256), b256, 0, stream>>>(
      bufD, ei, ei + EMP, ew, dinvE, bufB, EMP);
  k_epilogue<<<(N * 64 + 255) / 256, b256, 0, stream>>>(bufB, bufD, dinvE, nullptr, bufB, N, 64, 0);

  // attr / att heads into d_out, then in-place log-softmax
  {
    dim3 grid(1, (N + 63) / 64);
    k_gemm<<<grid, b256, 0, stream>>>(bufB, Wattr, battr, out_attr, N, 40, 64);
    k_gemm<<<grid, b256, 0, stream>>>(bufB, Watt, batt, out_att, N, 40, 64);
  }
  k_logsoftmax40<<<(N + 255) / 256, b256, 0, stream>>>(out_attr, N);
  k_logsoftmax40<<<(N + 255) / 256, b256, 0, stream>>>(out_att, N);

  // link prediction
  k_linkpred<<<(2 * ELP + 3) / 4, b256, 0, stream>>>(bufD, pos, neg, out_res, ELP);
}

// Round 2
// 845.285 us; speedup vs baseline: 1.4033x; 1.4033x over previous
//
#include <hip/hip_runtime.h>

// ---------------- CSR build: histogram, scan, fill ----------------

static __global__ void k_init(int* cntT, int* cntE, float* degE, int n) {
  int i = blockIdx.x * blockDim.x + threadIdx.x;
  if (i < n) { cntT[i] = 0; cntE[i] = 0; degE[i] = 1.0f; }  // self-loop weight 1
}

static __global__ void k_count(const int* __restrict__ tcol, const int* __restrict__ ecol,
                               const float* __restrict__ ew,
                               int* __restrict__ cntT, int* __restrict__ cntE,
                               float* __restrict__ degE, int E) {
  int e = blockIdx.x * blockDim.x + threadIdx.x;
  if (e < E) {
    atomicAdd(&cntT[tcol[e]], 1);
    atomicAdd(&cntE[ecol[e]], 1);
    atomicAdd(&degE[ecol[e]], ew[e]);
  }
}

static __global__ void k_dinv(const int* __restrict__ cntT, const float* __restrict__ degE,
                              float* __restrict__ dinvT, float* __restrict__ dinvE, int n) {
  int i = blockIdx.x * blockDim.x + threadIdx.x;
  if (i < n) {
    dinvT[i] = rsqrtf((float)cntT[i] + 1.0f);  // train edges: weight 1, + self loop
    dinvE[i] = rsqrtf(degE[i]);                // >= 1 always
  }
}

// one block per array (grid.x = 2), 1024 threads, exclusive scan of n counts
static __global__ __launch_bounds__(1024) void k_scan2(
    const int* __restrict__ cntT, int* __restrict__ ptrT, int* __restrict__ cursT,
    const int* __restrict__ cntE, int* __restrict__ ptrE, int* __restrict__ cursE, int n) {
  const int* cnt = blockIdx.x ? cntE : cntT;
  int* ptr  = blockIdx.x ? ptrE : ptrT;
  int* curs = blockIdx.x ? cursE : cursT;
  __shared__ int sums[1024];
  int T = blockDim.x, tid = threadIdx.x;
  int per = (n + T - 1) / T;
  int base = tid * per;
  int s = 0;
  for (int i = 0; i < per; ++i) { int idx = base + i; if (idx < n) s += cnt[idx]; }
  sums[tid] = s;
  __syncthreads();
  for (int off = 1; off < T; off <<= 1) {
    int v = (tid >= off) ? sums[tid - off] : 0;
    __syncthreads();
    sums[tid] += v;
    __syncthreads();
  }
  int pre = (tid > 0) ? sums[tid - 1] : 0;
  for (int i = 0; i < per; ++i) {
    int idx = base + i;
    if (idx < n) { ptr[idx] = pre; curs[idx] = pre; pre += cnt[idx]; }
  }
  if (tid == T - 1) ptr[n] = sums[T - 1];
}

static __global__ void k_fill(const int* __restrict__ trow, const int* __restrict__ tcol,
                              const int* __restrict__ erow, const int* __restrict__ ecol,
                              const float* __restrict__ ew, const float* __restrict__ dinvE,
                              int* __restrict__ cursT, int* __restrict__ cursE,
                              int* __restrict__ srcT, int* __restrict__ srcE,
                              float* __restrict__ wE, int E) {
  int e = blockIdx.x * blockDim.x + threadIdx.x;
  if (e >= E) return;
  {
    int c = tcol[e];
    int s = atomicAdd(&cursT[c], 1);
    srcT[s] = trow[e];
  }
  {
    int r = erow[e], c = ecol[e];
    int s = atomicAdd(&cursE[c], 1);
    srcE[s] = r;
    wE[s] = dinvE[r] * ew[e];
  }
}

// ---------------- gather-aggregate (CSR) with fused self-loop/bias/relu ----------------
// out[node] = (sum_j w_j * H[src_j] + dinv[node]*Hpre[node]) * dinv[node] + bias
// w_j = w ? w[j] : dinv[src_j]   (train edges: weight 1 -> only dinv[src])

template <int F, bool RELU>
static __global__ __launch_bounds__(256) void k_gather(
    const float* __restrict__ H, const int* __restrict__ rowptr,
    const int* __restrict__ src, const float* __restrict__ w,
    const float* __restrict__ dinv, const float* __restrict__ Hpre,
    const float* __restrict__ bias, float* __restrict__ out, int n) {
  const int G = 256 / F;
  int node = blockIdx.x * G + threadIdx.x / F;
  if (node >= n) return;
  int f = threadIdx.x % F;
  float d = dinv[node];
  float acc = Hpre[(size_t)node * F + f] * d;
  int j = rowptr[node], epos = rowptr[node + 1];
  for (; j + 1 < epos; j += 2) {
    int r0 = src[j], r1 = src[j + 1];
    float w0 = w ? w[j] : dinv[r0];
    float w1 = w ? w[j + 1] : dinv[r1];
    acc += H[(size_t)r0 * F + f] * w0;
    acc += H[(size_t)r1 * F + f] * w1;
  }
  if (j < epos) {
    int r = src[j];
    acc += H[(size_t)r * F + f] * (w ? w[j] : dinv[r]);
  }
  acc = acc * d + (bias ? bias[f] : 0.f);
  if (RELU) acc = fmaxf(acc, 0.f);
  out[(size_t)node * F + f] = acc;
}

// ---------------- fp32 tiled GEMM: C = A(MxK) @ B(KxN) (+bias) ----------------

static __global__ __launch_bounds__(256) void k_gemm(
    const float* __restrict__ A, const float* __restrict__ B,
    const float* __restrict__ bias, float* __restrict__ C,
    int M, int N, int K) {
  const int BM = 64, BN = 64, BK = 16;
  __shared__ float As[BK][BM + 4];
  __shared__ float Bs[BK][BN + 4];
  int tid = threadIdx.x;
  int tr = tid >> 4, tc = tid & 15;
  int brow = blockIdx.y * BM, bcol = blockIdx.x * BN;
  float acc[4][4] = {};
  for (int k0 = 0; k0 < K; k0 += BK) {
#pragma unroll
    for (int i = tid; i < BM * BK; i += 256) {
      int m = i >> 4, kk = i & 15;
      int gr = brow + m;
      As[kk][m] = (gr < M) ? A[(size_t)gr * K + k0 + kk] : 0.f;
    }
#pragma unroll
    for (int i = tid; i < BK * BN; i += 256) {
      int kk = i >> 6, n = i & 63;
      int gc = bcol + n;
      Bs[kk][n] = (gc < N) ? B[(size_t)(k0 + kk) * N + gc] : 0.f;
    }
    __syncthreads();
#pragma unroll
    for (int kk = 0; kk < BK; ++kk) {
      float a[4], b[4];
#pragma unroll
      for (int i = 0; i < 4; ++i) a[i] = As[kk][tr * 4 + i];
#pragma unroll
      for (int j = 0; j < 4; ++j) b[j] = Bs[kk][tc * 4 + j];
#pragma unroll
      for (int i = 0; i < 4; ++i)
#pragma unroll
        for (int j = 0; j < 4; ++j) acc[i][j] += a[i] * b[j];
    }
    __syncthreads();
  }
#pragma unroll
  for (int i = 0; i < 4; ++i) {
    int r = brow + tr * 4 + i;
    if (r >= M) continue;
#pragma unroll
    for (int j = 0; j < 4; ++j) {
      int c = bcol + tc * 4 + j;
      if (c < N) C[(size_t)r * N + c] = acc[i][j] + (bias ? bias[c] : 0.f);
    }
  }
}

// ---------------- log-softmax over 40 classes, in place ----------------

static __global__ void k_logsoftmax40(float* __restrict__ X, int n) {
  int i = blockIdx.x * blockDim.x + threadIdx.x;
  if (i >= n) return;
  float v[40];
  float m = -1e30f;
#pragma unroll
  for (int j = 0; j < 40; ++j) { v[j] = X[(size_t)i * 40 + j]; m = fmaxf(m, v[j]); }
  float s = 0.f;
#pragma unroll
  for (int j = 0; j < 40; ++j) s += expf(v[j] - m);
  float ls = logf(s) + m;
#pragma unroll
  for (int j = 0; j < 40; ++j) X[(size_t)i * 40 + j] = v[j] - ls;
}

// ---------------- link prediction: res[e] = dot64(h[dst], h[src]) ----------------

static __global__ void k_linkpred(const float* __restrict__ H2, const int* __restrict__ pos,
                                  const int* __restrict__ neg, float* __restrict__ res, int Elp) {
  int lane = threadIdx.x & 63;
  int e = blockIdx.x * (blockDim.x >> 6) + (threadIdx.x >> 6);
  if (e >= 2 * Elp) return;
  int a, b;
  if (e < Elp) { a = pos[e]; b = pos[Elp + e]; }
  else { int e2 = e - Elp; a = neg[e2]; b = neg[Elp + e2]; }
  float p = H2[(size_t)a * 64 + lane] * H2[(size_t)b * 64 + lane];
#pragma unroll
  for (int off = 32; off > 0; off >>= 1) p += __shfl_down(p, off, 64);
  if (lane == 0) res[e] = p;
}

// ---------------- launch ----------------

extern "C" void kernel_launch(void* const* d_in, const int* in_sizes, int n_in,
                              void* d_out, int out_size, void* d_ws, size_t ws_size,
                              hipStream_t stream) {
  const float* x    = (const float*)d_in[0];
  const int*   tp   = (const int*)d_in[1];   // train_pos_edge_index [2,EMP]
  const int*   ei   = (const int*)d_in[2];   // edge_index [2,EMP]
  const float* ew   = (const float*)d_in[3];
  const int*   pos  = (const int*)d_in[4];
  const int*   neg  = (const int*)d_in[5];
  const float* W1   = (const float*)d_in[6];
  const float* b1   = (const float*)d_in[7];
  const float* W2   = (const float*)d_in[8];
  const float* b2   = (const float*)d_in[9];
  const float* Wattr= (const float*)d_in[10];
  const float* battr= (const float*)d_in[11];
  const float* Watt = (const float*)d_in[12];
  const float* batt = (const float*)d_in[13];

  const int N   = in_sizes[0] / 512;  // 50000
  const int EMP = in_sizes[1] / 2;    // 800000
  const int ELP = in_sizes[4] / 2;    // 250000

  // workspace layout (4-byte units)
  float* ws = (float*)d_ws;
  float* dinvT = ws;                       // N
  float* dinvE = dinvT + N;                // N
  int* rowptrT = (int*)(dinvE + N);        // N+1
  int* rowptrE = rowptrT + (N + 1);        // N+1
  int* srcT    = rowptrE + (N + 1);        // EMP
  int* srcE    = srcT + EMP;               // EMP
  float* wE    = (float*)(srcE + EMP);     // EMP
  float* bufA  = wE + EMP;                 // N*128  (h1_pre -> h2_pre -> agg3)
  float* bufB  = bufA + (size_t)N * 128;   // N*128  (h)
  float* bufC  = bufB + (size_t)N * 128;   // N*64   (h2); temps overlay before step 9
  // temporaries (dead after k_fill) overlay bufC:
  int*   cntT  = (int*)bufC;               // N
  int*   cntE  = cntT + N;                 // N
  float* degE  = (float*)(cntE + N);       // N
  int*   cursT = (int*)(degE + N);         // N
  int*   cursE = cursT + N;                // N

  float* out_res  = (float*)d_out;
  float* out_attr = out_res + 2 * (size_t)ELP;
  float* out_att  = out_attr + (size_t)N * 40;

  dim3 b256(256);
  int gN = (N + 255) / 256;
  int gE = (EMP + 255) / 256;

  // CSR build + norms
  k_init<<<gN, b256, 0, stream>>>(cntT, cntE, degE, N);
  k_count<<<gE, b256, 0, stream>>>(tp + EMP, ei + EMP, ew, cntT, cntE, degE, EMP);
  k_dinv<<<gN, b256, 0, stream>>>(cntT, degE, dinvT, dinvE, N);
  k_scan2<<<2, 1024, 0, stream>>>(cntT, rowptrT, cursT, cntE, rowptrE, cursE, N);
  k_fill<<<gE, b256, 0, stream>>>(tp, tp + EMP, ei, ei + EMP, ew, dinvE,
                                  cursT, cursE, srcT, srcE, wE, EMP);

  // conv1: h1_pre = x @ W1 ; h = relu(Agg_T(h1_pre) + b1)
  {
    dim3 grid(2, (N + 63) / 64);
    k_gemm<<<grid, b256, 0, stream>>>(x, W1, nullptr, bufA, N, 128, 512);
  }
  k_gather<128, true><<<(N + 1) / 2, b256, 0, stream>>>(
      bufA, rowptrT, srcT, nullptr, dinvT, bufA, b1, bufB, N);

  // conv2: h2_pre = h @ W2 ; h2 = Agg_T(h2_pre) + b2
  {
    dim3 grid(1, (N + 63) / 64);
    k_gemm<<<grid, b256, 0, stream>>>(bufB, W2, nullptr, bufA, N, 64, 128);
  }
  k_gather<64, false><<<(N + 3) / 4, b256, 0, stream>>>(
      bufA, rowptrT, srcT, nullptr, dinvT, bufA, b2, bufC, N);

  // conv3/4 share aggregation: agg3 = Agg_E(h2) into bufA
  k_gather<64, false><<<(N + 3) / 4, b256, 0, stream>>>(
      bufC, rowptrE, srcE, wE, dinvE, bufC, nullptr, bufA, N);

  // heads
  {
    dim3 grid(1, (N + 63) / 64);
    k_gemm<<<grid, b256, 0, stream>>>(bufA, Wattr, battr, out_attr, N, 40, 64);
    k_gemm<<<grid, b256, 0, stream>>>(bufA, Watt, batt, out_att, N, 40, 64);
  }
  k_logsoftmax40<<<gN, b256, 0, stream>>>(out_attr, N);
  k_logsoftmax40<<<gN, b256, 0, stream>>>(out_att, N);

  // link prediction (h2 = bufC)
  k_linkpred<<<(2 * ELP + 3) / 4, b256, 0, stream>>>(bufC, pos, neg, out_res, ELP);
}

// Round 3
// 676.405 us; speedup vs baseline: 1.7536x; 1.2497x over previous
//
#include <hip/hip_runtime.h>

typedef short s16x8 __attribute__((ext_vector_type(8)));
typedef short s16x4 __attribute__((ext_vector_type(4)));
typedef float f32x4 __attribute__((ext_vector_type(4)));

static __device__ __forceinline__ unsigned short f2bf(float f) {
  unsigned u = __float_as_uint(f);
  u += 0x7fff + ((u >> 16) & 1);  // round-to-nearest-even
  return (unsigned short)(u >> 16);
}
static __device__ __forceinline__ float bf2f(unsigned short h) {
  return __uint_as_float(((unsigned)h) << 16);
}

// ---------------- CSR build: histogram, scan, fill ----------------

static __global__ void k_init(int* cntT, int* cntE, float* degE, int n) {
  int i = blockIdx.x * blockDim.x + threadIdx.x;
  if (i < n) { cntT[i] = 0; cntE[i] = 0; degE[i] = 1.0f; }
}

static __global__ void k_count(const int* __restrict__ tcol, const int* __restrict__ ecol,
                               const float* __restrict__ ew,
                               int* __restrict__ cntT, int* __restrict__ cntE,
                               float* __restrict__ degE, int E) {
  int e = blockIdx.x * blockDim.x + threadIdx.x;
  if (e < E) {
    atomicAdd(&cntT[tcol[e]], 1);
    atomicAdd(&cntE[ecol[e]], 1);
    atomicAdd(&degE[ecol[e]], ew[e]);
  }
}

static __global__ void k_dinv(const int* __restrict__ cntT, const float* __restrict__ degE,
                              float* __restrict__ dinvT, float* __restrict__ dinvE, int n) {
  int i = blockIdx.x * blockDim.x + threadIdx.x;
  if (i < n) {
    dinvT[i] = rsqrtf((float)cntT[i] + 1.0f);
    dinvE[i] = rsqrtf(degE[i]);
  }
}

static __global__ __launch_bounds__(1024) void k_scan2(
    const int* __restrict__ cntT, int* __restrict__ ptrT, int* __restrict__ cursT,
    const int* __restrict__ cntE, int* __restrict__ ptrE, int* __restrict__ cursE, int n) {
  const int* cnt = blockIdx.x ? cntE : cntT;
  int* ptr  = blockIdx.x ? ptrE : ptrT;
  int* curs = blockIdx.x ? cursE : cursT;
  __shared__ int sums[1024];
  int T = blockDim.x, tid = threadIdx.x;
  int per = (n + T - 1) / T;
  int base = tid * per;
  int s = 0;
  for (int i = 0; i < per; ++i) { int idx = base + i; if (idx < n) s += cnt[idx]; }
  sums[tid] = s;
  __syncthreads();
  for (int off = 1; off < T; off <<= 1) {
    int v = (tid >= off) ? sums[tid - off] : 0;
    __syncthreads();
    sums[tid] += v;
    __syncthreads();
  }
  int pre = (tid > 0) ? sums[tid - 1] : 0;
  for (int i = 0; i < per; ++i) {
    int idx = base + i;
    if (idx < n) { ptr[idx] = pre; curs[idx] = pre; pre += cnt[idx]; }
  }
  if (tid == T - 1) ptr[n] = sums[T - 1];
}

static __global__ void k_fill(const int* __restrict__ trow, const int* __restrict__ tcol,
                              const int* __restrict__ erow, const int* __restrict__ ecol,
                              const float* __restrict__ ew, const float* __restrict__ dinvE,
                              int* __restrict__ cursT, int* __restrict__ cursE,
                              int* __restrict__ srcT, int* __restrict__ srcE,
                              float* __restrict__ wE, int E) {
  int e = blockIdx.x * blockDim.x + threadIdx.x;
  if (e >= E) return;
  {
    int c = tcol[e];
    int s = atomicAdd(&cursT[c], 1);
    srcT[s] = trow[e];
  }
  {
    int r = erow[e], c = ecol[e];
    int s = atomicAdd(&cursE[c], 1);
    srcE[s] = r;
    wE[s] = dinvE[r] * ew[e];
  }
}

// ---------------- W1 pre-transpose + bf16 split: W[K][Nc] -> Wt_hi/lo [Nc][K] ----------------

static __global__ void k_cvtW(const float* __restrict__ W, unsigned short* __restrict__ Wh,
                              unsigned short* __restrict__ Wl, int K, int Nc) {
  int t = blockIdx.x * blockDim.x + threadIdx.x;
  if (t >= K * Nc) return;
  int k = t / Nc, c = t - k * Nc;
  float v = W[t];
  unsigned short hi = f2bf(v);
  Wh[(size_t)c * K + k] = hi;
  Wl[(size_t)c * K + k] = f2bf(v - bf2f(hi));
}

// ---------------- MFMA split-bf16 GEMM: C[M][128] = A[M][K] @ B[K][128] ----------------
// B given pre-transposed+split: Bh/Bl [128][K] bf16. A converted in-kernel during staging.

#define PADU 56  // LDS row stride in ushort (112 B: 16B-aligned, 2-way bank alias = free)

static __global__ __launch_bounds__(256) void k_gemm_mfma_split(
    const float* __restrict__ A, const unsigned short* __restrict__ Bh,
    const unsigned short* __restrict__ Bl, float* __restrict__ C, int M, int K) {
  __shared__ __align__(16) unsigned short Ah[128][PADU];
  __shared__ __align__(16) unsigned short Al[128][PADU];
  __shared__ __align__(16) unsigned short Bsh[128][PADU];
  __shared__ __align__(16) unsigned short Bsl[128][PADU];
  int tid = threadIdx.x;
  int lane = tid & 63, wid = tid >> 6;
  int wr = wid >> 1, wc = wid & 1;
  int l15 = lane & 15, l4 = lane >> 4;
  int brow = blockIdx.x * 128;
  f32x4 acc[4][4] = {};

  for (int k0 = 0; k0 < K; k0 += 32) {
    __syncthreads();
    // stage A tile 128x32 f32 -> hi/lo bf16
#pragma unroll
    for (int q = 0; q < 4; ++q) {
      int idx = tid + q * 256;
      int r = idx >> 3, c4 = (idx & 7) * 4;
      int gr = brow + r;
      float4 v = (gr < M) ? *(const float4*)&A[(size_t)gr * K + k0 + c4]
                          : make_float4(0.f, 0.f, 0.f, 0.f);
      unsigned short h0 = f2bf(v.x), h1 = f2bf(v.y), h2 = f2bf(v.z), h3 = f2bf(v.w);
      s16x4 hv = {(short)h0, (short)h1, (short)h2, (short)h3};
      s16x4 lv = {(short)f2bf(v.x - bf2f(h0)), (short)f2bf(v.y - bf2f(h1)),
                  (short)f2bf(v.z - bf2f(h2)), (short)f2bf(v.w - bf2f(h3))};
      *(s16x4*)&Ah[r][c4] = hv;
      *(s16x4*)&Al[r][c4] = lv;
    }
    // stage B tile: 128 cols x 32 k (bf16, already transposed)
#pragma unroll
    for (int q = 0; q < 2; ++q) {
      int idx = tid + q * 256;
      int r = idx >> 2, c8 = (idx & 3) * 8;
      *(s16x8*)&Bsh[r][c8] = *(const s16x8*)&Bh[(size_t)r * K + k0 + c8];
      *(s16x8*)&Bsl[r][c8] = *(const s16x8*)&Bl[(size_t)r * K + k0 + c8];
    }
    __syncthreads();
    s16x8 afh[4], afl[4], bfh[4], bfl[4];
#pragma unroll
    for (int m = 0; m < 4; ++m) {
      int r = wr * 64 + m * 16 + l15;
      afh[m] = *(const s16x8*)&Ah[r][l4 * 8];
      afl[m] = *(const s16x8*)&Al[r][l4 * 8];
    }
#pragma unroll
    for (int n = 0; n < 4; ++n) {
      int c = wc * 64 + n * 16 + l15;
      bfh[n] = *(const s16x8*)&Bsh[c][l4 * 8];
      bfl[n] = *(const s16x8*)&Bsl[c][l4 * 8];
    }
#pragma unroll
    for (int m = 0; m < 4; ++m)
#pragma unroll
      for (int n = 0; n < 4; ++n) {
        acc[m][n] = __builtin_amdgcn_mfma_f32_16x16x32_bf16(afh[m], bfh[n], acc[m][n], 0, 0, 0);
        acc[m][n] = __builtin_amdgcn_mfma_f32_16x16x32_bf16(afl[m], bfh[n], acc[m][n], 0, 0, 0);
        acc[m][n] = __builtin_amdgcn_mfma_f32_16x16x32_bf16(afh[m], bfl[n], acc[m][n], 0, 0, 0);
      }
  }
#pragma unroll
  for (int m = 0; m < 4; ++m) {
    int rbase = brow + wr * 64 + m * 16 + l4 * 4;
#pragma unroll
    for (int n = 0; n < 4; ++n) {
      int c = wc * 64 + n * 16 + l15;
#pragma unroll
      for (int j = 0; j < 4; ++j) {
        int r = rbase + j;
        if (r < M) C[(size_t)r * 128 + c] = acc[m][n][j];
      }
    }
  }
}

// ---------------- gather-aggregate (CSR), float4-vectorized ----------------
// out[node] = (sum_j w_j * H[src_j] + dinv[node]*Hpre[node]) * dinv[node] + bias

template <int F, bool RELU>
static __global__ __launch_bounds__(256) void k_gather4(
    const float* __restrict__ H, const int* __restrict__ rowptr,
    const int* __restrict__ src, const float* __restrict__ w,
    const float* __restrict__ dinv, const float* __restrict__ Hpre,
    const float* __restrict__ bias, float* __restrict__ out, int n) {
  const int L = F / 4;
  int node = blockIdx.x * (256 / L) + threadIdx.x / L;
  if (node >= n) return;
  int f4 = (threadIdx.x % L) * 4;
  float d = dinv[node];
  float4 hp = *(const float4*)&Hpre[(size_t)node * F + f4];
  float ax = hp.x * d, ay = hp.y * d, az = hp.z * d, aw = hp.w * d;
  int j = rowptr[node], e = rowptr[node + 1];
  for (; j + 1 < e; j += 2) {
    int r0 = src[j], r1 = src[j + 1];
    float w0 = w ? w[j] : dinv[r0];
    float w1 = w ? w[j + 1] : dinv[r1];
    float4 v0 = *(const float4*)&H[(size_t)r0 * F + f4];
    float4 v1 = *(const float4*)&H[(size_t)r1 * F + f4];
    ax += v0.x * w0 + v1.x * w1;
    ay += v0.y * w0 + v1.y * w1;
    az += v0.z * w0 + v1.z * w1;
    aw += v0.w * w0 + v1.w * w1;
  }
  if (j < e) {
    int r = src[j];
    float wj = w ? w[j] : dinv[r];
    float4 v = *(const float4*)&H[(size_t)r * F + f4];
    ax += v.x * wj; ay += v.y * wj; az += v.z * wj; aw += v.w * wj;
  }
  float bx = 0, by = 0, bz = 0, bw = 0;
  if (bias) { float4 bb = *(const float4*)&bias[f4]; bx = bb.x; by = bb.y; bz = bb.z; bw = bb.w; }
  ax = ax * d + bx; ay = ay * d + by; az = az * d + bz; aw = aw * d + bw;
  if (RELU) { ax = fmaxf(ax, 0.f); ay = fmaxf(ay, 0.f); az = fmaxf(az, 0.f); aw = fmaxf(aw, 0.f); }
  float4 o; o.x = ax; o.y = ay; o.z = az; o.w = aw;
  *(float4*)&out[(size_t)node * F + f4] = o;
}

// ---------------- fp32 tiled GEMM (small N: conv2 + heads) ----------------

static __global__ __launch_bounds__(256) void k_gemm(
    const float* __restrict__ A, const float* __restrict__ B,
    const float* __restrict__ bias, float* __restrict__ C,
    int M, int N, int K) {
  const int BM = 64, BN = 64, BK = 16;
  __shared__ float As[BK][BM + 4];
  __shared__ float Bs[BK][BN + 4];
  int tid = threadIdx.x;
  int tr = tid >> 4, tc = tid & 15;
  int brow = blockIdx.y * BM, bcol = blockIdx.x * BN;
  float acc[4][4] = {};
  for (int k0 = 0; k0 < K; k0 += BK) {
#pragma unroll
    for (int i = tid; i < BM * BK; i += 256) {
      int m = i >> 4, kk = i & 15;
      int gr = brow + m;
      As[kk][m] = (gr < M) ? A[(size_t)gr * K + k0 + kk] : 0.f;
    }
#pragma unroll
    for (int i = tid; i < BK * BN; i += 256) {
      int kk = i >> 6, n = i & 63;
      int gc = bcol + n;
      Bs[kk][n] = (gc < N) ? B[(size_t)(k0 + kk) * N + gc] : 0.f;
    }
    __syncthreads();
#pragma unroll
    for (int kk = 0; kk < BK; ++kk) {
      float a[4], b[4];
#pragma unroll
      for (int i = 0; i < 4; ++i) a[i] = As[kk][tr * 4 + i];
#pragma unroll
      for (int j = 0; j < 4; ++j) b[j] = Bs[kk][tc * 4 + j];
#pragma unroll
      for (int i = 0; i < 4; ++i)
#pragma unroll
        for (int j = 0; j < 4; ++j) acc[i][j] += a[i] * b[j];
    }
    __syncthreads();
  }
#pragma unroll
  for (int i = 0; i < 4; ++i) {
    int r = brow + tr * 4 + i;
    if (r >= M) continue;
#pragma unroll
    for (int j = 0; j < 4; ++j) {
      int c = bcol + tc * 4 + j;
      if (c < N) C[(size_t)r * N + c] = acc[i][j] + (bias ? bias[c] : 0.f);
    }
  }
}

// ---------------- log-softmax over 40 classes, in place ----------------

static __global__ void k_logsoftmax40(float* __restrict__ X, int n) {
  int i = blockIdx.x * blockDim.x + threadIdx.x;
  if (i >= n) return;
  float4 v[10];
#pragma unroll
  for (int q = 0; q < 10; ++q) v[q] = *(const float4*)&X[(size_t)i * 40 + q * 4];
  float m = -1e30f;
#pragma unroll
  for (int q = 0; q < 10; ++q)
    m = fmaxf(m, fmaxf(fmaxf(v[q].x, v[q].y), fmaxf(v[q].z, v[q].w)));
  float s = 0.f;
#pragma unroll
  for (int q = 0; q < 10; ++q)
    s += expf(v[q].x - m) + expf(v[q].y - m) + expf(v[q].z - m) + expf(v[q].w - m);
  float ls = logf(s) + m;
#pragma unroll
  for (int q = 0; q < 10; ++q) {
    float4 o; o.x = v[q].x - ls; o.y = v[q].y - ls; o.z = v[q].z - ls; o.w = v[q].w - ls;
    *(float4*)&X[(size_t)i * 40 + q * 4] = o;
  }
}

// ---------------- link prediction: res[e] = dot64(h[dst], h[src]) ----------------

static __global__ __launch_bounds__(256) void k_linkpred4(
    const float* __restrict__ H2, const int* __restrict__ pos,
    const int* __restrict__ neg, float* __restrict__ res, int Elp) {
  int t = blockIdx.x * 256 + threadIdx.x;
  int e = t >> 4, f4 = (t & 15) * 4;
  if (e >= 2 * Elp) return;
  int a, b;
  if (e < Elp) { a = pos[e]; b = pos[Elp + e]; }
  else { int e2 = e - Elp; a = neg[e2]; b = neg[Elp + e2]; }
  float4 va = *(const float4*)&H2[(size_t)a * 64 + f4];
  float4 vb = *(const float4*)&H2[(size_t)b * 64 + f4];
  float p = va.x * vb.x + va.y * vb.y + va.z * vb.z + va.w * vb.w;
  p += __shfl_xor(p, 1);
  p += __shfl_xor(p, 2);
  p += __shfl_xor(p, 4);
  p += __shfl_xor(p, 8);
  if ((t & 15) == 0) res[e] = p;
}

// ---------------- launch ----------------

extern "C" void kernel_launch(void* const* d_in, const int* in_sizes, int n_in,
                              void* d_out, int out_size, void* d_ws, size_t ws_size,
                              hipStream_t stream) {
  const float* x    = (const float*)d_in[0];
  const int*   tp   = (const int*)d_in[1];
  const int*   ei   = (const int*)d_in[2];
  const float* ew   = (const float*)d_in[3];
  const int*   pos  = (const int*)d_in[4];
  const int*   neg  = (const int*)d_in[5];
  const float* W1   = (const float*)d_in[6];
  const float* b1   = (const float*)d_in[7];
  const float* W2   = (const float*)d_in[8];
  const float* b2   = (const float*)d_in[9];
  const float* Wattr= (const float*)d_in[10];
  const float* battr= (const float*)d_in[11];
  const float* Watt = (const float*)d_in[12];
  const float* batt = (const float*)d_in[13];

  const int N   = in_sizes[0] / 512;  // 50000
  const int EMP = in_sizes[1] / 2;    // 800000
  const int ELP = in_sizes[4] / 2;    // 250000

  // workspace layout (float units, every region 16B-aligned)
  float* ws = (float*)d_ws;
  float* dinvT = ws;                          // N
  float* dinvE = dinvT + N;                   // N
  int* rowptrT = (int*)(dinvE + N);           // N+1 (+pad)
  int* rowptrE = rowptrT + (N + 4);           // N+1 (+pad)
  int* srcT    = rowptrE + (N + 4);           // EMP
  int* srcE    = srcT + EMP;                  // EMP
  float* wE    = (float*)(srcE + EMP);        // EMP
  unsigned short* W1h = (unsigned short*)(wE + EMP);   // 128*512 bf16
  unsigned short* W1l = W1h + 512 * 128;               // 128*512 bf16
  float* bufA  = (float*)(W1l + 512 * 128);   // N*128
  float* bufB  = bufA + (size_t)N * 128;      // N*128
  float* bufC  = bufB + (size_t)N * 128;      // N*64
  int*   cntT  = (int*)bufC;                  // temporaries overlay bufC
  int*   cntE  = cntT + N;
  float* degE  = (float*)(cntE + N);
  int*   cursT = (int*)(degE + N);
  int*   cursE = cursT + N;

  float* out_res  = (float*)d_out;
  float* out_attr = out_res + 2 * (size_t)ELP;
  float* out_att  = out_attr + (size_t)N * 40;

  dim3 b256(256);
  int gN = (N + 255) / 256;
  int gE = (EMP + 255) / 256;

  // CSR build + norms (+ W1 convert, independent)
  k_init<<<gN, b256, 0, stream>>>(cntT, cntE, degE, N);
  k_cvtW<<<(512 * 128 + 255) / 256, b256, 0, stream>>>(W1, W1h, W1l, 512, 128);
  k_count<<<gE, b256, 0, stream>>>(tp + EMP, ei + EMP, ew, cntT, cntE, degE, EMP);
  k_dinv<<<gN, b256, 0, stream>>>(cntT, degE, dinvT, dinvE, N);
  k_scan2<<<2, 1024, 0, stream>>>(cntT, rowptrT, cursT, cntE, rowptrE, cursE, N);
  k_fill<<<gE, b256, 0, stream>>>(tp, tp + EMP, ei, ei + EMP, ew, dinvE,
                                  cursT, cursE, srcT, srcE, wE, EMP);

  // conv1: h1_pre = x @ W1 (MFMA split-bf16) ; h = relu(Agg_T(h1_pre) + b1)
  k_gemm_mfma_split<<<(N + 127) / 128, b256, 0, stream>>>(x, W1h, W1l, bufA, N, 512);
  k_gather4<128, true><<<(N + 7) / 8, b256, 0, stream>>>(
      bufA, rowptrT, srcT, nullptr, dinvT, bufA, b1, bufB, N);

  // conv2: h2_pre = h @ W2 ; h2 = Agg_T(h2_pre) + b2
  {
    dim3 grid(1, (N + 63) / 64);
    k_gemm<<<grid, b256, 0, stream>>>(bufB, W2, nullptr, bufA, N, 64, 128);
  }
  k_gather4<64, false><<<(N + 15) / 16, b256, 0, stream>>>(
      bufA, rowptrT, srcT, nullptr, dinvT, bufA, b2, bufC, N);

  // conv3/4 share aggregation: agg3 = Agg_E(h2) into bufA
  k_gather4<64, false><<<(N + 15) / 16, b256, 0, stream>>>(
      bufC, rowptrE, srcE, wE, dinvE, bufC, nullptr, bufA, N);

  // heads
  {
    dim3 grid(1, (N + 63) / 64);
    k_gemm<<<grid, b256, 0, stream>>>(bufA, Wattr, battr, out_attr, N, 40, 64);
    k_gemm<<<grid, b256, 0, stream>>>(bufA, Watt, batt, out_att, N, 40, 64);
  }
  k_logsoftmax40<<<gN, b256, 0, stream>>>(out_attr, N);
  k_logsoftmax40<<<gN, b256, 0, stream>>>(out_att, N);

  // link prediction (h2 = bufC)
  k_linkpred4<<<(2 * ELP * 16 + 255) / 256, b256, 0, stream>>>(bufC, pos, neg, out_res, ELP);
}

// Round 4
// 432.524 us; speedup vs baseline: 2.7425x; 1.5639x over previous
//
#include <hip/hip_runtime.h>

typedef short s16x8 __attribute__((ext_vector_type(8)));
typedef short s16x4 __attribute__((ext_vector_type(4)));
typedef float f32x4 __attribute__((ext_vector_type(4)));

static __device__ __forceinline__ unsigned short f2bf(float f) {
  unsigned u = __float_as_uint(f);
  u += 0x7fff + ((u >> 16) & 1);  // round-to-nearest-even
  return (unsigned short)(u >> 16);
}
static __device__ __forceinline__ float bf2f(unsigned short h) {
  return __uint_as_float(((unsigned)h) << 16);
}

// ---------------- CSR build ----------------

static __global__ void k_init(int* cntT, int* cntE, int n) {
  int i = blockIdx.x * blockDim.x + threadIdx.x;
  if (i < n) { cntT[i] = 0; cntE[i] = 0; }
}

// counts + per-edge rank (rank = old count value, from the atomic return)
static __global__ void k_count(const int* __restrict__ tcol, const int* __restrict__ ecol,
                               int* __restrict__ cntT, int* __restrict__ cntE,
                               int* __restrict__ rankT, int* __restrict__ rankE, int E) {
  int e = blockIdx.x * blockDim.x + threadIdx.x;
  if (e < E) {
    rankT[e] = atomicAdd(&cntT[tcol[e]], 1);
    rankE[e] = atomicAdd(&cntE[ecol[e]], 1);
  }
}

// 3-phase exclusive scan over both count arrays (grid.y selects array)
static __global__ __launch_bounds__(256) void k_scanA(
    const int* __restrict__ cntT, const int* __restrict__ cntE,
    int* __restrict__ bsum, int n, int nb) {
  const int* cnt = blockIdx.y ? cntE : cntT;
  int tid = threadIdx.x;
  int base = blockIdx.x * 1024 + tid * 4;
  int s = 0;
#pragma unroll
  for (int q = 0; q < 4; ++q) { int i = base + q; if (i < n) s += cnt[i]; }
  __shared__ int red[256];
  red[tid] = s;
  __syncthreads();
  for (int off = 128; off > 0; off >>= 1) {
    if (tid < off) red[tid] += red[tid + off];
    __syncthreads();
  }
  if (tid == 0) bsum[blockIdx.y * nb + blockIdx.x] = red[0];
}

static __global__ void k_scanB(int* bsum, int* ptrT, int* ptrE, int nb, int n) {
  int a = threadIdx.x;
  if (a > 1) return;
  int* bs = bsum + a * nb;
  int run = 0;
  for (int i = 0; i < nb; ++i) { int c = bs[i]; bs[i] = run; run += c; }
  (a ? ptrE : ptrT)[n] = run;
}

static __global__ __launch_bounds__(256) void k_scanC(
    const int* __restrict__ cntT, const int* __restrict__ cntE,
    const int* __restrict__ bsum, int* __restrict__ ptrT, int* __restrict__ ptrE,
    int n, int nb) {
  const int* cnt = blockIdx.y ? cntE : cntT;
  int* ptr = blockIdx.y ? ptrE : ptrT;
  int tid = threadIdx.x;
  int pre = bsum[blockIdx.y * nb + blockIdx.x];
  int base = blockIdx.x * 1024 + tid * 4;
  int v[4];
  int s = 0;
#pragma unroll
  for (int q = 0; q < 4; ++q) { int i = base + q; v[q] = (i < n) ? cnt[i] : 0; s += v[q]; }
  __shared__ int red[256];
  red[tid] = s;
  __syncthreads();
  for (int off = 1; off < 256; off <<= 1) {
    int t = (tid >= off) ? red[tid - off] : 0;
    __syncthreads();
    red[tid] += t;
    __syncthreads();
  }
  int run = pre + (tid ? red[tid - 1] : 0);
#pragma unroll
  for (int q = 0; q < 4; ++q) {
    int i = base + q;
    if (i < n) ptr[i] = run;
    run += v[q];
  }
}

// atomic-free fill: slot = ptr[col] + rank
static __global__ void k_fill(const int* __restrict__ trow, const int* __restrict__ tcol,
                              const int* __restrict__ erow, const int* __restrict__ ecol,
                              const float* __restrict__ ew,
                              const int* __restrict__ ptrT, const int* __restrict__ ptrE,
                              const int* __restrict__ rankT, const int* __restrict__ rankE,
                              int* __restrict__ srcT, int2* __restrict__ srcwE, int E) {
  int e = blockIdx.x * blockDim.x + threadIdx.x;
  if (e >= E) return;
  srcT[ptrT[tcol[e]] + rankT[e]] = trow[e];
  int2 p;
  p.x = erow[e];
  p.y = __float_as_int(ew[e]);
  srcwE[ptrE[ecol[e]] + rankE[e]] = p;
}

// dinvT from counts; dinvE from CSR segment-sum of ew
static __global__ void k_dinv2(const int* __restrict__ cntT, const int2* __restrict__ srcwE,
                               const int* __restrict__ ptrE,
                               float* __restrict__ dinvT, float* __restrict__ dinvE, int n) {
  int i = blockIdx.x * blockDim.x + threadIdx.x;
  if (i >= n) return;
  dinvT[i] = rsqrtf((float)cntT[i] + 1.0f);
  float s = 1.0f;  // self loop
  int e = ptrE[i + 1];
  for (int j = ptrE[i]; j < e; ++j) s += __int_as_float(srcwE[j].y);
  dinvE[i] = rsqrtf(s);
}

// ---------------- W1 pre-transpose + bf16 split ----------------

static __global__ void k_cvtW(const float* __restrict__ W, unsigned short* __restrict__ Wh,
                              unsigned short* __restrict__ Wl, int K, int Nc) {
  int t = blockIdx.x * blockDim.x + threadIdx.x;
  if (t >= K * Nc) return;
  int k = t / Nc, c = t - k * Nc;
  float v = W[t];
  unsigned short hi = f2bf(v);
  Wh[(size_t)c * K + k] = hi;
  Wl[(size_t)c * K + k] = f2bf(v - bf2f(hi));
}

// ---------------- MFMA split-bf16 GEMM: C[M][128] = A[M][K] @ B[K][128] ----------------

#define PADU 56  // LDS row stride in ushort (112 B: 16B-aligned, 2-way bank alias = free)

static __global__ __launch_bounds__(256) void k_gemm_mfma_split(
    const float* __restrict__ A, const unsigned short* __restrict__ Bh,
    const unsigned short* __restrict__ Bl, float* __restrict__ C, int M, int K) {
  __shared__ __align__(16) unsigned short Ah[128][PADU];
  __shared__ __align__(16) unsigned short Al[128][PADU];
  __shared__ __align__(16) unsigned short Bsh[128][PADU];
  __shared__ __align__(16) unsigned short Bsl[128][PADU];
  int tid = threadIdx.x;
  int lane = tid & 63, wid = tid >> 6;
  int wr = wid >> 1, wc = wid & 1;
  int l15 = lane & 15, l4 = lane >> 4;
  int brow = blockIdx.x * 128;
  f32x4 acc[4][4] = {};

  for (int k0 = 0; k0 < K; k0 += 32) {
    __syncthreads();
#pragma unroll
    for (int q = 0; q < 4; ++q) {
      int idx = tid + q * 256;
      int r = idx >> 3, c4 = (idx & 7) * 4;
      int gr = brow + r;
      float4 v = (gr < M) ? *(const float4*)&A[(size_t)gr * K + k0 + c4]
                          : make_float4(0.f, 0.f, 0.f, 0.f);
      unsigned short h0 = f2bf(v.x), h1 = f2bf(v.y), h2 = f2bf(v.z), h3 = f2bf(v.w);
      s16x4 hv = {(short)h0, (short)h1, (short)h2, (short)h3};
      s16x4 lv = {(short)f2bf(v.x - bf2f(h0)), (short)f2bf(v.y - bf2f(h1)),
                  (short)f2bf(v.z - bf2f(h2)), (short)f2bf(v.w - bf2f(h3))};
      *(s16x4*)&Ah[r][c4] = hv;
      *(s16x4*)&Al[r][c4] = lv;
    }
#pragma unroll
    for (int q = 0; q < 2; ++q) {
      int idx = tid + q * 256;
      int r = idx >> 2, c8 = (idx & 3) * 8;
      *(s16x8*)&Bsh[r][c8] = *(const s16x8*)&Bh[(size_t)r * K + k0 + c8];
      *(s16x8*)&Bsl[r][c8] = *(const s16x8*)&Bl[(size_t)r * K + k0 + c8];
    }
    __syncthreads();
    s16x8 afh[4], afl[4], bfh[4], bfl[4];
#pragma unroll
    for (int m = 0; m < 4; ++m) {
      int r = wr * 64 + m * 16 + l15;
      afh[m] = *(const s16x8*)&Ah[r][l4 * 8];
      afl[m] = *(const s16x8*)&Al[r][l4 * 8];
    }
#pragma unroll
    for (int n = 0; n < 4; ++n) {
      int c = wc * 64 + n * 16 + l15;
      bfh[n] = *(const s16x8*)&Bsh[c][l4 * 8];
      bfl[n] = *(const s16x8*)&Bsl[c][l4 * 8];
    }
#pragma unroll
    for (int m = 0; m < 4; ++m)
#pragma unroll
      for (int n = 0; n < 4; ++n) {
        acc[m][n] = __builtin_amdgcn_mfma_f32_16x16x32_bf16(afh[m], bfh[n], acc[m][n], 0, 0, 0);
        acc[m][n] = __builtin_amdgcn_mfma_f32_16x16x32_bf16(afl[m], bfh[n], acc[m][n], 0, 0, 0);
        acc[m][n] = __builtin_amdgcn_mfma_f32_16x16x32_bf16(afh[m], bfl[n], acc[m][n], 0, 0, 0);
      }
  }
#pragma unroll
  for (int m = 0; m < 4; ++m) {
    int rbase = brow + wr * 64 + m * 16 + l4 * 4;
#pragma unroll
    for (int n = 0; n < 4; ++n) {
      int c = wc * 64 + n * 16 + l15;
#pragma unroll
      for (int j = 0; j < 4; ++j) {
        int r = rbase + j;
        if (r < M) C[(size_t)r * 128 + c] = acc[m][n][j];
      }
    }
  }
}

// ---------------- gather-aggregate (CSR), float4-vectorized ----------------
// out[node] = (sum_j w_j * H[src_j] + dinv[node]*Hpre[node]) * dinv[node] + bias
// unweighted: w_j = dinv[src]; weighted: w_j = dinv[src]*ew_j

template <int F, bool RELU, bool WEIGHTED>
static __global__ __launch_bounds__(256) void k_gather4(
    const float* __restrict__ H, const int* __restrict__ rowptr,
    const int* __restrict__ src, const int2* __restrict__ srcw,
    const float* __restrict__ dinv, const float* __restrict__ Hpre,
    const float* __restrict__ bias, float* __restrict__ out, int n) {
  const int L = F / 4;
  int node = blockIdx.x * (256 / L) + threadIdx.x / L;
  if (node >= n) return;
  int f4 = (threadIdx.x % L) * 4;
  float d = dinv[node];
  float4 hp = *(const float4*)&Hpre[(size_t)node * F + f4];
  float ax = hp.x * d, ay = hp.y * d, az = hp.z * d, aw = hp.w * d;
  int j = rowptr[node], e = rowptr[node + 1];
  for (; j + 1 < e; j += 2) {
    int r0, r1;
    float w0, w1;
    if (WEIGHTED) {
      int2 a = srcw[j], b = srcw[j + 1];
      r0 = a.x; r1 = b.x;
      w0 = dinv[r0] * __int_as_float(a.y);
      w1 = dinv[r1] * __int_as_float(b.y);
    } else {
      r0 = src[j]; r1 = src[j + 1];
      w0 = dinv[r0]; w1 = dinv[r1];
    }
    float4 v0 = *(const float4*)&H[(size_t)r0 * F + f4];
    float4 v1 = *(const float4*)&H[(size_t)r1 * F + f4];
    ax += v0.x * w0 + v1.x * w1;
    ay += v0.y * w0 + v1.y * w1;
    az += v0.z * w0 + v1.z * w1;
    aw += v0.w * w0 + v1.w * w1;
  }
  if (j < e) {
    int r;
    float wj;
    if (WEIGHTED) { int2 a = srcw[j]; r = a.x; wj = dinv[r] * __int_as_float(a.y); }
    else { r = src[j]; wj = dinv[r]; }
    float4 v = *(const float4*)&H[(size_t)r * F + f4];
    ax += v.x * wj; ay += v.y * wj; az += v.z * wj; aw += v.w * wj;
  }
  float bx = 0, by = 0, bz = 0, bw = 0;
  if (bias) { float4 bb = *(const float4*)&bias[f4]; bx = bb.x; by = bb.y; bz = bb.z; bw = bb.w; }
  ax = ax * d + bx; ay = ay * d + by; az = az * d + bz; aw = aw * d + bw;
  if (RELU) { ax = fmaxf(ax, 0.f); ay = fmaxf(ay, 0.f); az = fmaxf(az, 0.f); aw = fmaxf(aw, 0.f); }
  float4 o; o.x = ax; o.y = ay; o.z = az; o.w = aw;
  *(float4*)&out[(size_t)node * F + f4] = o;
}

// ---------------- fp32 tiled GEMM (small N: conv2 + heads) ----------------

static __global__ __launch_bounds__(256) void k_gemm(
    const float* __restrict__ A, const float* __restrict__ B,
    const float* __restrict__ bias, float* __restrict__ C,
    int M, int N, int K) {
  const int BM = 64, BN = 64, BK = 16;
  __shared__ float As[BK][BM + 4];
  __shared__ float Bs[BK][BN + 4];
  int tid = threadIdx.x;
  int tr = tid >> 4, tc = tid & 15;
  int brow = blockIdx.y * BM, bcol = blockIdx.x * BN;
  float acc[4][4] = {};
  for (int k0 = 0; k0 < K; k0 += BK) {
#pragma unroll
    for (int i = tid; i < BM * BK; i += 256) {
      int m = i >> 4, kk = i & 15;
      int gr = brow + m;
      As[kk][m] = (gr < M) ? A[(size_t)gr * K + k0 + kk] : 0.f;
    }
#pragma unroll
    for (int i = tid; i < BK * BN; i += 256) {
      int kk = i >> 6, n = i & 63;
      int gc = bcol + n;
      Bs[kk][n] = (gc < N) ? B[(size_t)(k0 + kk) * N + gc] : 0.f;
    }
    __syncthreads();
#pragma unroll
    for (int kk = 0; kk < BK; ++kk) {
      float a[4], b[4];
#pragma unroll
      for (int i = 0; i < 4; ++i) a[i] = As[kk][tr * 4 + i];
#pragma unroll
      for (int j = 0; j < 4; ++j) b[j] = Bs[kk][tc * 4 + j];
#pragma unroll
      for (int i = 0; i < 4; ++i)
#pragma unroll
        for (int j = 0; j < 4; ++j) acc[i][j] += a[i] * b[j];
    }
    __syncthreads();
  }
#pragma unroll
  for (int i = 0; i < 4; ++i) {
    int r = brow + tr * 4 + i;
    if (r >= M) continue;
#pragma unroll
    for (int j = 0; j < 4; ++j) {
      int c = bcol + tc * 4 + j;
      if (c < N) C[(size_t)r * N + c] = acc[i][j] + (bias ? bias[c] : 0.f);
    }
  }
}

// ---------------- log-softmax over 40 classes, in place ----------------

static __global__ void k_logsoftmax40(float* __restrict__ X, int n) {
  int i = blockIdx.x * blockDim.x + threadIdx.x;
  if (i >= n) return;
  float4 v[10];
#pragma unroll
  for (int q = 0; q < 10; ++q) v[q] = *(const float4*)&X[(size_t)i * 40 + q * 4];
  float m = -1e30f;
#pragma unroll
  for (int q = 0; q < 10; ++q)
    m = fmaxf(m, fmaxf(fmaxf(v[q].x, v[q].y), fmaxf(v[q].z, v[q].w)));
  float s = 0.f;
#pragma unroll
  for (int q = 0; q < 10; ++q)
    s += expf(v[q].x - m) + expf(v[q].y - m) + expf(v[q].z - m) + expf(v[q].w - m);
  float ls = logf(s) + m;
#pragma unroll
  for (int q = 0; q < 10; ++q) {
    float4 o; o.x = v[q].x - ls; o.y = v[q].y - ls; o.z = v[q].z - ls; o.w = v[q].w - ls;
    *(float4*)&X[(size_t)i * 40 + q * 4] = o;
  }
}

// ---------------- link prediction ----------------

static __global__ __launch_bounds__(256) void k_linkpred4(
    const float* __restrict__ H2, const int* __restrict__ pos,
    const int* __restrict__ neg, float* __restrict__ res, int Elp) {
  int t = blockIdx.x * 256 + threadIdx.x;
  int e = t >> 4, f4 = (t & 15) * 4;
  if (e >= 2 * Elp) return;
  int a, b;
  if (e < Elp) { a = pos[e]; b = pos[Elp + e]; }
  else { int e2 = e - Elp; a = neg[e2]; b = neg[Elp + e2]; }
  float4 va = *(const float4*)&H2[(size_t)a * 64 + f4];
  float4 vb = *(const float4*)&H2[(size_t)b * 64 + f4];
  float p = va.x * vb.x + va.y * vb.y + va.z * vb.z + va.w * vb.w;
  p += __shfl_xor(p, 1);
  p += __shfl_xor(p, 2);
  p += __shfl_xor(p, 4);
  p += __shfl_xor(p, 8);
  if ((t & 15) == 0) res[e] = p;
}

// ---------------- launch ----------------

extern "C" void kernel_launch(void* const* d_in, const int* in_sizes, int n_in,
                              void* d_out, int out_size, void* d_ws, size_t ws_size,
                              hipStream_t stream) {
  const float* x    = (const float*)d_in[0];
  const int*   tp   = (const int*)d_in[1];
  const int*   ei   = (const int*)d_in[2];
  const float* ew   = (const float*)d_in[3];
  const int*   pos  = (const int*)d_in[4];
  const int*   neg  = (const int*)d_in[5];
  const float* W1   = (const float*)d_in[6];
  const float* b1   = (const float*)d_in[7];
  const float* W2   = (const float*)d_in[8];
  const float* b2   = (const float*)d_in[9];
  const float* Wattr= (const float*)d_in[10];
  const float* battr= (const float*)d_in[11];
  const float* Watt = (const float*)d_in[12];
  const float* batt = (const float*)d_in[13];

  const int N   = in_sizes[0] / 512;  // 50000
  const int EMP = in_sizes[1] / 2;    // 800000
  const int ELP = in_sizes[4] / 2;    // 250000
  const int NB  = (N + 1023) / 1024;  // scan blocks per array

  // workspace layout (4B units, 16B-aligned regions)
  float* ws = (float*)d_ws;
  float* dinvT = ws;                          // N
  float* dinvE = dinvT + N;                   // N
  int* rowptrT = (int*)(dinvE + N);           // N+1 (+pad)
  int* rowptrE = rowptrT + (N + 4);           // N+1 (+pad)
  int* srcT    = rowptrE + (N + 4);           // EMP
  int2* srcwE  = (int2*)(srcT + EMP);         // EMP int2
  int* bsum    = (int*)(srcwE + EMP);         // 2*NB (+pad)
  unsigned short* W1h = (unsigned short*)(bsum + 128);  // 512*128 bf16
  unsigned short* W1l = W1h + 512 * 128;                // 512*128 bf16
  float* bufA  = (float*)(W1l + 512 * 128);   // N*128
  float* bufB  = bufA + (size_t)N * 128;      // N*128
  float* bufC  = bufB + (size_t)N * 128;      // N*64
  // overlays (dead before their hosts are written):
  int* rankT = (int*)bufA;                    // EMP (dead after k_fill; bufA written later)
  int* rankE = rankT + EMP;                   // EMP
  int* cntT  = (int*)bufB;                    // N (dead after k_dinv2; bufB written later)
  int* cntE  = cntT + N;                      // N

  float* out_res  = (float*)d_out;
  float* out_attr = out_res + 2 * (size_t)ELP;
  float* out_att  = out_attr + (size_t)N * 40;

  dim3 b256(256);
  int gN = (N + 255) / 256;
  int gE = (EMP + 255) / 256;

  // CSR build + norms (+ W1 convert, independent)
  k_init<<<gN, b256, 0, stream>>>(cntT, cntE, N);
  k_cvtW<<<(512 * 128 + 255) / 256, b256, 0, stream>>>(W1, W1h, W1l, 512, 128);
  k_count<<<gE, b256, 0, stream>>>(tp + EMP, ei + EMP, cntT, cntE, rankT, rankE, EMP);
  {
    dim3 gs(NB, 2);
    k_scanA<<<gs, b256, 0, stream>>>(cntT, cntE, bsum, N, NB);
    k_scanB<<<1, 64, 0, stream>>>(bsum, rowptrT, rowptrE, NB, N);
    k_scanC<<<gs, b256, 0, stream>>>(cntT, cntE, bsum, rowptrT, rowptrE, N, NB);
  }
  k_fill<<<gE, b256, 0, stream>>>(tp, tp + EMP, ei, ei + EMP, ew,
                                  rowptrT, rowptrE, rankT, rankE, srcT, srcwE, EMP);
  k_dinv2<<<gN, b256, 0, stream>>>(cntT, srcwE, rowptrE, dinvT, dinvE, N);

  // conv1: h1_pre = x @ W1 (MFMA split-bf16) ; h = relu(Agg_T(h1_pre) + b1)
  k_gemm_mfma_split<<<(N + 127) / 128, b256, 0, stream>>>(x, W1h, W1l, bufA, N, 512);
  k_gather4<128, true, false><<<(N + 7) / 8, b256, 0, stream>>>(
      bufA, rowptrT, srcT, nullptr, dinvT, bufA, b1, bufB, N);

  // conv2: h2_pre = h @ W2 ; h2 = Agg_T(h2_pre) + b2
  {
    dim3 grid(1, (N + 63) / 64);
    k_gemm<<<grid, b256, 0, stream>>>(bufB, W2, nullptr, bufA, N, 64, 128);
  }
  k_gather4<64, false, false><<<(N + 15) / 16, b256, 0, stream>>>(
      bufA, rowptrT, srcT, nullptr, dinvT, bufA, b2, bufC, N);

  // conv3/4 share aggregation: agg3 = Agg_E(h2) into bufA
  k_gather4<64, false, true><<<(N + 15) / 16, b256, 0, stream>>>(
      bufC, rowptrE, nullptr, srcwE, dinvE, bufC, nullptr, bufA, N);

  // heads
  {
    dim3 grid(1, (N + 63) / 64);
    k_gemm<<<grid, b256, 0, stream>>>(bufA, Wattr, battr, out_attr, N, 40, 64);
    k_gemm<<<grid, b256, 0, stream>>>(bufA, Watt, batt, out_att, N, 40, 64);
  }
  k_logsoftmax40<<<gN, b256, 0, stream>>>(out_attr, N);
  k_logsoftmax40<<<gN, b256, 0, stream>>>(out_att, N);

  // link prediction (h2 = bufC)
  k_linkpred4<<<(2 * ELP * 16 + 255) / 256, b256, 0, stream>>>(bufC, pos, neg, out_res, ELP);
}